// Round 4
// baseline (82.489 us; speedup 1.0000x reference)
//
#include <hip/hip_runtime.h>

// Problem constants: v (targets y), v_pred (queries x) are [4, 8192, 3] fp32.
#define BB 4
#define NN 8192
#define MM 8192
#define BN (BB * NN)

#define QB   64                  // queries per chamfer block (2 A-tiles)
#define CBLK 512                 // chamfer block threads = 8 waves
#define NBLK ((NN / QB) * BB)    // 128 x 4 = 512 blocks
#define JTW  (MM / 32 / 8)       // 32 j-tiles per wave (each wave: 1024 targets)

typedef __bf16 bf16x8 __attribute__((ext_vector_type(8)));
typedef float  f32x16 __attribute__((ext_vector_type(16)));

// ws layout (uint4 units):
//   xfrag: [0, BN*2)        A-flavor frags, 1 MB. index(point p, part h) =
//          (p>>5)*64 + h*32 + (p&31)   (tile-major, part-major-by-32)
//   yfrag: [BN*2, BN*4)     B-flavor frags, 1 MB, same indexing
//   sums : 16 floats at byte offset 2 MB (zeroed by prepack)
//   cnt  : 1 int after sums (zeroed by prepack)
//
// v_mfma_f32_32x32x16_bf16 (layouts verified by R0 absmax=0.0):
//   A: row=lane&31, k=(lane>>5)*8+e;  B: col=lane&31, k=(lane>>5)*8+e
//   D: col=lane&31, row=(r&3)+8*(r>>2)+4*(lane>>5)
// K-slot packing: k0..3 {2x0h,2x0h,2x0l,2x0l}x{y0h,y0l,y0h,y0l} = 2*x0*y0;
// k4..7 dim1; k8..11 dim2; k12,13 {-xx_h,-xx_l}x{1,1}; k14,15 {1,1}x{-yy_h,-yy_l}
// => with C=0: D = 2x.y - xx - yy = -d2.  min d2 = -max D.

static __device__ inline void split_bf(float v, __bf16& h, __bf16& l) {
    h = (__bf16)v;
    l = (__bf16)(v - (float)h);
}

__global__ __launch_bounds__(256) void prepack(
    const float* __restrict__ x,    // v_pred (queries) -> A flavor
    const float* __restrict__ y,    // v (targets)      -> B flavor
    uint4* __restrict__ ws4,
    float* __restrict__ sums,
    int* __restrict__ cnt)
{
    const int id  = blockIdx.x * 256 + threadIdx.x;   // point index 0..BN-1
    const int isB = blockIdx.y;                       // 0: A flavor, 1: B flavor

    // zero the reduction slots + counter (removes any poison dependence)
    if (blockIdx.x == 0 && isB == 0 && threadIdx.x < 17) {
        if (threadIdx.x < 16) sums[threadIdx.x] = 0.0f;
        else *cnt = 0;
    }

    const float* s = isB ? y : x;
    float c0 = s[3*id+0], c1 = s[3*id+1], c2 = s[3*id+2];
    float nss = -__builtin_fmaf(c2, c2, __builtin_fmaf(c1, c1, c0*c0));
    __bf16 sh, sl; split_bf(nss, sh, sl);
    const __bf16 one = (__bf16)1.0f;
    bf16x8 g0, g1;
    if (!isB) {                       // A flavor: split 2*x
        __bf16 h0,l0,h1,l1,h2,l2;
        split_bf(2.0f*c0, h0, l0);
        split_bf(2.0f*c1, h1, l1);
        split_bf(2.0f*c2, h2, l2);
        g0 = bf16x8{h0,h0,l0,l0,h1,h1,l1,l1};
        g1 = bf16x8{h2,h2,l2,l2,sh,sl,one,one};
    } else {                          // B flavor: split y
        __bf16 h0,l0,h1,l1,h2,l2;
        split_bf(c0, h0, l0);
        split_bf(c1, h1, l1);
        split_bf(c2, h2, l2);
        g0 = bf16x8{h0,l0,h0,l0,h1,l1,h1,l1};
        g1 = bf16x8{h2,l2,h2,l2,one,one,sh,sl};
    }
    uint4* dst = ws4 + (size_t)(isB ? BN*2 : 0);
    const int base = (id >> 5) * 64 + (id & 31);
    dst[base]      = __builtin_bit_cast(uint4, g0);
    dst[base + 32] = __builtin_bit_cast(uint4, g1);
}

__global__ __launch_bounds__(CBLK, 4) void chamfer(
    const uint4* __restrict__ ws4,
    float* __restrict__ out,
    float* __restrict__ sums,
    int* __restrict__ cnt)
{
    const int t   = threadIdx.x;
    const int l   = t & 63;
    const int w   = t >> 6;          // wave 0..7
    const int hi  = l >> 5;          // frag part
    const int c32 = l & 31;
    const int ib  = blockIdx.x;      // query chunk 0..127
    const int b   = blockIdx.y;      // batch

    const uint4* xf = ws4;
    const uint4* yf = ws4 + (size_t)BN * 2;

    // A fragments for this block's 64 queries (2 tiles), held in regs
    const int xtile = b * (NN/32) + ib * 2;
    const bf16x8 a0 = __builtin_bit_cast(bf16x8, xf[(size_t)xtile*64 + hi*32 + c32]);
    const bf16x8 a1 = __builtin_bit_cast(bf16x8, xf[(size_t)(xtile+1)*64 + hi*32 + c32]);

    // this wave's 32 target tiles (contiguous 1024 targets)
    const uint4* yb = yf + ((size_t)b * (MM/32) + w * JTW) * 64 + hi*32 + c32;

    f32x16 z;
#pragma unroll
    for (int r = 0; r < 16; ++r) z[r] = 0.0f;
    f32x16 best0, best1;
#pragma unroll
    for (int r = 0; r < 16; ++r) { best0[r] = -3.4e38f; best1[r] = -3.4e38f; }

#pragma unroll 1
    for (int jt = 0; jt < JTW; jt += 2) {
        const bf16x8 bf0 = __builtin_bit_cast(bf16x8, yb[(size_t)jt * 64]);
        const bf16x8 bf1 = __builtin_bit_cast(bf16x8, yb[(size_t)jt * 64 + 64]);
        f32x16 p = __builtin_amdgcn_mfma_f32_32x32x16_bf16(a0, bf0, z, 0, 0, 0);
        f32x16 q = __builtin_amdgcn_mfma_f32_32x32x16_bf16(a0, bf1, z, 0, 0, 0);
#pragma unroll
        for (int r = 0; r < 16; ++r)
            best0[r] = fmaxf(fmaxf(best0[r], p[r]), q[r]);   // v_max3_f32
        p = __builtin_amdgcn_mfma_f32_32x32x16_bf16(a1, bf0, z, 0, 0, 0);
        q = __builtin_amdgcn_mfma_f32_32x32x16_bf16(a1, bf1, z, 0, 0, 0);
#pragma unroll
        for (int r = 0; r < 16; ++r)
            best1[r] = fmaxf(fmaxf(best1[r], p[r]), q[r]);
    }

    // ---- in-block combine: col-reduce (32 targets) then across 8 waves ----
    __shared__ float red[8][QB];
#pragma unroll
    for (int at = 0; at < 2; ++at) {
        const f32x16 bb = at ? best1 : best0;
#pragma unroll
        for (int r = 0; r < 16; ++r) {
            float v = bb[r];
            v = fmaxf(v, __shfl_xor(v, 1, 64));
            v = fmaxf(v, __shfl_xor(v, 2, 64));
            v = fmaxf(v, __shfl_xor(v, 4, 64));
            v = fmaxf(v, __shfl_xor(v, 8, 64));
            v = fmaxf(v, __shfl_xor(v, 16, 64));
            if (c32 == 0) {
                const int R = (r & 3) + 8 * (r >> 2) + 4 * hi;
                red[w][at * 32 + R] = v;
            }
        }
    }
    __syncthreads();

    if (w == 0) {
        // lane l owns query l: max over waves, then block sum of min-d2
        float m = red[0][l];
#pragma unroll
        for (int k = 1; k < 8; ++k) m = fmaxf(m, red[k][l]);
        float part = -m;                       // min d2 of this query
        for (int off = 32; off > 0; off >>= 1)
            part += __shfl_down(part, off, 64);

        int old = 0;
        if (l == 0) {
            atomicAdd(&sums[(ib * BB + b) & 15], part);
            __threadfence();
            old = atomicAdd(cnt, 1);
        }
        old = __shfl(old, 0, 64);
        if (old == NBLK - 1) {                 // last block finalizes
            float tot = 0.0f;
            if (l < 16) tot = atomicAdd(&sums[l], 0.0f);   // coherent read
            tot += __shfl_down(tot, 8, 64);
            tot += __shfl_down(tot, 4, 64);
            tot += __shfl_down(tot, 2, 64);
            tot += __shfl_down(tot, 1, 64);
            if (l == 0) out[0] = tot * (1.0f / (float)BN);
        }
    }
}

extern "C" void kernel_launch(void* const* d_in, const int* in_sizes, int n_in,
                              void* d_out, int out_size, void* d_ws, size_t ws_size,
                              hipStream_t stream) {
    // setup_inputs order: d_in[0] = v (targets y), d_in[1] = v_pred (queries x)
    const float* v      = (const float*)d_in[0];
    const float* v_pred = (const float*)d_in[1];
    float* out = (float*)d_out;

    uint4* ws4   = (uint4*)d_ws;
    float* sums  = (float*)((char*)d_ws + ((size_t)BN * 4) * 16);  // after 2 MB of frags
    int*   cnt   = (int*)(sums + 16);

    prepack<<<dim3(BN / 256, 2), 256, 0, stream>>>(v_pred, v, ws4, sums, cnt);
    chamfer<<<dim3(NN / QB, BB), CBLK, 0, stream>>>(ws4, out, sums, cnt);
}